// Round 9
// baseline (258.200 us; speedup 1.0000x reference)
//
#include <hip/hip_runtime.h>

// Voxel merge (2x2x2, blocks i*4+j*2+k) + mask + LayerNorm(768) + GEMM [65536,768]x[768,192].
// v8.1: tile-level deep pipeline, 1 block/CU.  (v8 + fix: mask read missing (T&1)<<5 offset)
//   - Each block: 4 tiles of 16 merged rows. Tile x-footprint = 4 contiguous 12KB chunks
//     (+1KB mask row) -> 13 x 1KB global_load_lds wave-issues, no per-element address math.
//   - Double-buffered raw-f32 LDS (2 x 50176 B); tile t+1's 26KB stays in the vmcnt queue
//     across ALL of tile t's compute: raw s_barrier + counted s_waitcnt vmcnt(N), never 0
//     mid-loop (T3/T4). Queue depth per CU ~26KB >> 9KB needed to saturate HBM.
//   - MFMA A-frags read directly from raw LDS (f32) with a source-pre-swizzle (m173) to kill
//     the 768B-stride bank conflict; mask+bf16-cvt in regs; LN folded into the epilogue
//     (out = rs*(xm@(g.*W)) - mu*rs*u + v), per-lane stats -> 2 shfl_xor, no extra barriers.
#define NOUT 192
#define M_TOTAL 65536
#define OUT0 (M_TOTAL * NOUT)
#define CHUNK 12288
#define TILE_LDS (4 * CHUNK + 1024)   // 50176 B

typedef __attribute__((ext_vector_type(8))) short  short8;
typedef __attribute__((ext_vector_type(4))) float  f32x4;

__device__ __forceinline__ unsigned short f2bf(float f) {
    union { float f; unsigned u; } a; a.f = f;
    unsigned r = a.u + 0x7FFFu + ((a.u >> 16) & 1u);  // RNE
    return (unsigned short)(r >> 16);
}

__device__ __forceinline__ void gload16(void* lds, const void* g) {
    __builtin_amdgcn_global_load_lds((const __attribute__((address_space(1))) void*)g,
                                     (__attribute__((address_space(3))) void*)lds, 16, 0, 0);
}

// Wb[(ks*12+fn)*64 + l] (short8) = bf16(gamma[k] * W[k,n]), k=ks*32+(l>>4)*8+e, n=fn*16+(l&15)
__global__ __launch_bounds__(256) void prepw_kernel(const float* __restrict__ Wm,
                                                    const float* __restrict__ gamma,
                                                    unsigned short* __restrict__ Wb) {
    int t = blockIdx.x * 256 + threadIdx.x;
    if (t >= 24 * 12 * 512) return;
    int e  = t & 7;
    int l  = (t >> 3) & 63;
    int f  = t >> 9;
    int fn = f % 12;
    int ks = f / 12;
    int k  = ks * 32 + ((l >> 4) << 3) + e;
    Wb[t] = f2bf(gamma[k] * Wm[k * NOUT + fn * 16 + (l & 15)]);
}

// uv[o] = { sum_c gamma[c]*W[c,o], sum_c beta[c]*W[c,o] } — 192 blocks
__global__ __launch_bounds__(256) void prepuv_kernel(const float* __restrict__ Wm,
                                                     const float* __restrict__ gamma,
                                                     const float* __restrict__ beta,
                                                     float2* __restrict__ uv) {
    __shared__ float2 red[4];
    const int o = blockIdx.x, tid = threadIdx.x;
    float u = 0.f, v = 0.f;
    for (int c = tid; c < 768; c += 256) {
        const float w = Wm[c * NOUT + o];
        u = fmaf(gamma[c], w, u);
        v = fmaf(beta[c],  w, v);
    }
#pragma unroll
    for (int off = 32; off >= 1; off >>= 1) {
        u += __shfl_xor(u, off);
        v += __shfl_xor(v, off);
    }
    if ((tid & 63) == 0) red[tid >> 6] = make_float2(u, v);
    __syncthreads();
    if (tid == 0) {
        float2 a = red[0];
        a.x += red[1].x + red[2].x + red[3].x;
        a.y += red[1].y + red[2].y + red[3].y;
        uv[o] = a;
    }
}

__global__ __launch_bounds__(256, 1) void fused_kernel(
    const float* __restrict__ x, const float* __restrict__ mask,
    const unsigned short* __restrict__ Wb, const float2* __restrict__ uv,
    float* __restrict__ out)
{
    __shared__ __align__(16) char raw[2 * TILE_LDS];   // 100352 B -> 1 block/CU

    const int tid = threadIdx.x, l = tid & 63, wv = tid >> 6;
    const int lr = l & 15, q = l >> 4;
    const int T0 = blockIdx.x << 2;          // 1024 blocks x 4 tiles
    const int fxor = (lr >> 1) & 7;          // ds-read swizzle (matches write-side involution)

    // this wave's 3 col-fragments: cols wv*48 + c*16 + lr
    float2 uvv[3];
#pragma unroll
    for (int c = 0; c < 3; ++c) uvv[c] = uv[wv * 48 + c * 16 + lr];

    // pre-swizzled per-lane global source offsets (bytes within a 12KB chunk):
    // LDS 16B-unit s holds global unit s ^ (((s/24)>>2)&7)  [involution]
    int gsrco[12];
#pragma unroll
    for (int ld = 0; ld < 12; ++ld) {
        const int s = (ld << 6) + l;
        gsrco[ld] = (s ^ (((s / 24) >> 2) & 7)) << 4;
    }

    const short8* Wv = (const short8*)Wb;
    const int bbase = wv * 192 + l;

    // issue one tile's global->LDS DMA: this wave's 12KB chunk (+wave0: 1KB mask row)
    auto issue_tile = [&](int T, int bb) {
        const int rgb = T << 4;
        const int w2b = (T & 1) << 4;
        const int h2 = (rgb >> 5) & 31, d2 = (rgb >> 10) & 31, b = rgb >> 15;
        const int d = (d2 << 1) + (wv >> 1), h = (h2 << 1) + (wv & 1);
        const char* gsrc = (const char*)(x +
            ((((size_t)b * 64 + d) * 64 + h) * 64 + ((size_t)w2b << 1)) * 96);
        char* ldsb = raw + bb * TILE_LDS + wv * CHUNK;
#pragma unroll
        for (int ld = 0; ld < 12; ++ld)
            gload16(ldsb + (ld << 10), gsrc + gsrco[ld]);
        if (wv == 0) {   // masks: lane l -> (ij=l>>4) (d,h)-row, 16B at w=(l&15)*4
            const int ij = l >> 4;
            const int dm = (d2 << 1) + (ij >> 1), hm = (h2 << 1) + (ij & 1);
            const char* msrc = (const char*)(mask +
                (((size_t)b * 64 + dm) * 64 + hm) * 64 + ((l & 15) << 2));
            gload16(raw + bb * TILE_LDS + 4 * CHUNK, msrc);
        }
    };

    // ---------------- prologue: fill both buffers ----------------
    issue_tile(T0 + 0, 0);
    issue_tile(T0 + 1, 1);
    asm volatile("s_waitcnt vmcnt(12)" ::: "memory");   // tile0 done; tile1 stays in flight
    __builtin_amdgcn_sched_barrier(0);
    __builtin_amdgcn_s_barrier();
    __builtin_amdgcn_sched_barrier(0);

    int cur = 0;
#pragma unroll 1
    for (int t = 0; t < 4; ++t) {
        const int T = T0 + t;
        const char* cb = raw + cur * TILE_LDS;
        const float* ml = (const float*)(cb + 4 * CHUNK);

        // per-tile masks from LDS: mk[bi] = mask of (row lr, sub-voxel bi)
        // absolute w = (T&1)*32 + 2*lr + (bi&1)  [v8 bug: missing (T&1)<<5]
        const int wmo = (T & 1) << 5;
        float mk[8];
#pragma unroll
        for (int bi = 0; bi < 8; ++bi)
            mk[bi] = ml[(bi >> 1) * 64 + wmo + (lr << 1) + (bi & 1)];

        // ---- K-loop: A from raw LDS (mask+cvt in regs), B from L2, 3 MFMA/ks ----
        f32x4 acc[3] = {};
        float s = 0.f, s2 = 0.f;
#pragma unroll
        for (int ks = 0; ks < 24; ++ks) {
            const int bi = ks / 3, m = ks % 3;
            const int u16 = ((lr << 1) + (bi & 1)) * 24 + (m << 3) + (q << 1);
            const char* ap = cb + (bi >> 1) * CHUNK;
            const float4 r0 = *(const float4*)(ap + ((u16 ^ fxor) << 4));
            const float4 r1 = *(const float4*)(ap + (((u16 + 1) ^ fxor) << 4));
            const float mkv = mk[bi];
            const float u0x = r0.x * mkv, u0y = r0.y * mkv, u0z = r0.z * mkv, u0w = r0.w * mkv;
            const float u1x = r1.x * mkv, u1y = r1.y * mkv, u1z = r1.z * mkv, u1w = r1.w * mkv;
            s  += (u0x + u0y) + (u0z + u0w) + (u1x + u1y) + (u1z + u1w);
            s2 += (u0x*u0x + u0y*u0y) + (u0z*u0z + u0w*u0w)
                + (u1x*u1x + u1y*u1y) + (u1z*u1z + u1w*u1w);
            short8 fa;
            fa[0] = (short)f2bf(u0x); fa[1] = (short)f2bf(u0y);
            fa[2] = (short)f2bf(u0z); fa[3] = (short)f2bf(u0w);
            fa[4] = (short)f2bf(u1x); fa[5] = (short)f2bf(u1y);
            fa[6] = (short)f2bf(u1z); fa[7] = (short)f2bf(u1w);
            const short8 b0 = Wv[ks * 768 + bbase];
            const short8 b1 = Wv[ks * 768 + bbase + 64];
            const short8 b2 = Wv[ks * 768 + bbase + 128];
            acc[0] = __builtin_amdgcn_mfma_f32_16x16x32_bf16(fa, b0, acc[0], 0, 0, 0);
            acc[1] = __builtin_amdgcn_mfma_f32_16x16x32_bf16(fa, b1, acc[1], 0, 0, 0);
            acc[2] = __builtin_amdgcn_mfma_f32_16x16x32_bf16(fa, b2, acc[2], 0, 0, 0);
        }

        // all waves done reading buf[cur]; refill it with tile t+2 (loads stay in flight)
        __builtin_amdgcn_s_barrier();
        __builtin_amdgcn_sched_barrier(0);
        if (t + 2 < 4) issue_tile(T + 2, cur);

        // ---- epilogue: stats reduce (4 lanes/row), LN fold, store ----
        s  += __shfl_xor(s, 16);  s  += __shfl_xor(s, 32);
        s2 += __shfl_xor(s2, 16); s2 += __shfl_xor(s2, 32);
        const float mu   = s * (1.f / 768.f);
        const float var  = s2 * (1.f / 768.f) - mu * mu;
        const float rs   = rsqrtf(var + 1e-5f);
        const float murs = mu * rs;
#pragma unroll
        for (int j = 0; j < 4; ++j) {
            const int row = (q << 2) + j;            // D: col = lane&15, row = (l>>4)*4+j
            const float rsj   = __shfl(rs,   row);   // stats for row r live in lane r (lr==r)
            const float mursj = __shfl(murs, row);
            float* orow = out + (size_t)((T << 4) + row) * NOUT;
#pragma unroll
            for (int c = 0; c < 3; ++c)
                orow[wv * 48 + c * 16 + lr] =
                    fmaf(rsj, acc[c][j], fmaf(-mursj, uvv[c].x, uvv[c].y));
        }
        if (wv == 0 && q == 0) {
            const float mo = fmaxf(fmaxf(fmaxf(mk[0], mk[1]), fmaxf(mk[2], mk[3])),
                                   fmaxf(fmaxf(mk[4], mk[5]), fmaxf(mk[6], mk[7])));
            out[OUT0 + (T << 4) + lr] = (mo > 0.f) ? 1.f : 0.f;
        }

        if (t < 3) {   // wait for tile t+1 (leaves tile t+2's loads + recent stores outstanding)
            asm volatile("s_waitcnt vmcnt(24)" ::: "memory");
            __builtin_amdgcn_sched_barrier(0);
            __builtin_amdgcn_s_barrier();
            __builtin_amdgcn_sched_barrier(0);
        }
        cur ^= 1;
    }
}

extern "C" void kernel_launch(void* const* d_in, const int* in_sizes, int n_in,
                              void* d_out, int out_size, void* d_ws, size_t ws_size,
                              hipStream_t stream) {
    const float* x     = (const float*)d_in[0];
    const float* mask  = (const float*)d_in[1];
    const float* gamma = (const float*)d_in[2];
    const float* beta  = (const float*)d_in[3];
    const float* Wm    = (const float*)d_in[4];
    float* out = (float*)d_out;

    unsigned short* Wb  = (unsigned short*)d_ws;               // 294912 B
    float2*         uvp = (float2*)((char*)d_ws + 294912);     // 1536 B

    prepw_kernel <<<576,  256, 0, stream>>>(Wm, gamma, Wb);
    prepuv_kernel<<<192,  256, 0, stream>>>(Wm, gamma, beta, uvp);
    fused_kernel <<<1024, 256, 0, stream>>>(x, mask, Wb, uvp, out);
}